// Round 9
// baseline (321.625 us; speedup 1.0000x reference)
//
#include <hip/hip_runtime.h>
#include <hip/hip_bf16.h>
#include <math.h>

#define NN 50000       // nodes
#define NE 800000      // raw edges
#define ET 850000      // edges incl. self-loops
#define FIN 128
#define HTOT 128       // 4 heads * 32
#define OUTC 8
#define NB ((NN + 255) / 256)   // 196 scan blocks
#define XLD 132        // padded LDS stride for x tile

__device__ __forceinline__ float lrelu(float v){ return v > 0.f ? v : 0.2f*v; }
__device__ __forceinline__ float eluf(float v){ return v > 0.f ? v : expm1f(v); }

__device__ __forceinline__ unsigned pack_bf16(float a, float b){
  __hip_bfloat16 ha = __float2bfloat16(a);
  __hip_bfloat16 hb = __float2bfloat16(b);
  const unsigned short ua = *(const unsigned short*)&ha;
  const unsigned short ub = *(const unsigned short*)&hb;
  return ((unsigned)ub << 16) | (unsigned)ua;
}
__device__ __forceinline__ float bf_lo(unsigned u){ return __int_as_float((int)(u << 16)); }
__device__ __forceinline__ float bf_hi(unsigned u){ return __int_as_float((int)(u & 0xffff0000u)); }

// ---------------- Layer-1 GEMM (x @ W1) + alpha_src/alpha_dst; h1 bf16-packed ----------------
__global__ __launch_bounds__(256) void k_gemm(
    const float* __restrict__ x, const float* __restrict__ W1,
    const float* __restrict__ a_src1, const float* __restrict__ a_dst1,
    unsigned* __restrict__ h1b, float* __restrict__ as1, float* __restrict__ ad1)
{
  __shared__ float xl[64 * XLD];
  const int t = threadIdx.x;
  const int r0 = blockIdx.x * 64;

  #pragma unroll
  for (int i = 0; i < 8; ++i) {
    const int f   = i*256 + t;
    const int row = f >> 5;
    const int c4  = f & 31;
    const int gr  = r0 + row;
    float4 v = make_float4(0.f,0.f,0.f,0.f);
    if (gr < NN) v = *(const float4*)&x[(size_t)gr*FIN + c4*4];
    *(float4*)&xl[row*XLD + c4*4] = v;
  }
  __syncthreads();

  const int tx = t & 15, ty = t >> 4;
  const int c0a = tx*4;
  const int c0b = 64 + tx*4;

  float acc[4][8];
  #pragma unroll
  for (int i=0;i<4;++i)
    #pragma unroll
    for (int j=0;j<8;++j) acc[i][j] = 0.f;

  for (int k = 0; k < 128; k += 4) {
    float4 xv[4];
    #pragma unroll
    for (int i=0;i<4;++i)
      xv[i] = *(const float4*)&xl[(ty*4+i)*XLD + k];
    #pragma unroll
    for (int kk = 0; kk < 4; ++kk) {
      const float4 wa = *(const float4*)&W1[(size_t)(k+kk)*128 + c0a];
      const float4 wb = *(const float4*)&W1[(size_t)(k+kk)*128 + c0b];
      #pragma unroll
      for (int i=0;i<4;++i) {
        const float xk = (kk==0)?xv[i].x:(kk==1)?xv[i].y:(kk==2)?xv[i].z:xv[i].w;
        acc[i][0] += xk*wa.x; acc[i][1] += xk*wa.y; acc[i][2] += xk*wa.z; acc[i][3] += xk*wa.w;
        acc[i][4] += xk*wb.x; acc[i][5] += xk*wb.y; acc[i][6] += xk*wb.z; acc[i][7] += xk*wb.w;
      }
    }
  }

  #pragma unroll
  for (int i=0;i<4;++i) {
    const int gr = r0 + ty*4 + i;
    if (gr < NN) {
      uint2 ua, ub;
      ua.x = pack_bf16(acc[i][0], acc[i][1]);
      ua.y = pack_bf16(acc[i][2], acc[i][3]);
      ub.x = pack_bf16(acc[i][4], acc[i][5]);
      ub.y = pack_bf16(acc[i][6], acc[i][7]);
      *(uint2*)&h1b[(size_t)gr*64 + tx*2]      = ua;
      *(uint2*)&h1b[(size_t)gr*64 + 32 + tx*2] = ub;
    }
  }

  float sa[4], sb[4], da[4], db[4];
  {
    const float4 v0 = *(const float4*)&a_src1[c0a];
    const float4 v1 = *(const float4*)&a_src1[c0b];
    const float4 v2 = *(const float4*)&a_dst1[c0a];
    const float4 v3 = *(const float4*)&a_dst1[c0b];
    sa[0]=v0.x; sa[1]=v0.y; sa[2]=v0.z; sa[3]=v0.w;
    sb[0]=v1.x; sb[1]=v1.y; sb[2]=v1.z; sb[3]=v1.w;
    da[0]=v2.x; da[1]=v2.y; da[2]=v2.z; da[3]=v2.w;
    db[0]=v3.x; db[1]=v3.y; db[2]=v3.z; db[3]=v3.w;
  }
  const int ha = tx >> 3;
  #pragma unroll
  for (int i=0;i<4;++i) {
    float psa = 0.f, pda = 0.f, psb = 0.f, pdb = 0.f;
    #pragma unroll
    for (int j=0;j<4;++j) {
      psa += acc[i][j]  *sa[j]; pda += acc[i][j]  *da[j];
      psb += acc[i][4+j]*sb[j]; pdb += acc[i][4+j]*db[j];
    }
    psa += __shfl_xor(psa,1); psa += __shfl_xor(psa,2); psa += __shfl_xor(psa,4);
    pda += __shfl_xor(pda,1); pda += __shfl_xor(pda,2); pda += __shfl_xor(pda,4);
    psb += __shfl_xor(psb,1); psb += __shfl_xor(psb,2); psb += __shfl_xor(psb,4);
    pdb += __shfl_xor(pdb,1); pdb += __shfl_xor(pdb,2); pdb += __shfl_xor(pdb,4);
    const int gr = r0 + ty*4 + i;
    if ((tx & 7) == 0 && gr < NN) {
      as1[(size_t)gr*4 + ha]     = psa;
      ad1[(size_t)gr*4 + ha]     = pda;
      as1[(size_t)gr*4 + ha + 2] = psb;
      ad1[(size_t)gr*4 + ha + 2] = pdb;
    }
  }
}

// ---------------- CSR build ----------------
__global__ __launch_bounds__(256) void k_hist(const int* __restrict__ ei,
                                              unsigned* __restrict__ counts)
{
  const int e = blockIdx.x*256 + threadIdx.x;
  if (e >= ET) return;
  const int d = (e < NE) ? ei[NE + e] : (e - NE);
  atomicAdd(&counts[d], 1u);
}

__global__ __launch_bounds__(256) void k_scan_part(const unsigned* __restrict__ counts,
                                                   unsigned* __restrict__ bsum)
{
  const int idx = blockIdx.x*256 + threadIdx.x;
  unsigned v = (idx < NN) ? counts[idx] : 0u;
  #pragma unroll
  for (int o = 1; o < 64; o <<= 1) v += __shfl_xor(v, o);
  __shared__ unsigned wsum[4];
  const int lane = threadIdx.x & 63, wid = threadIdx.x >> 6;
  if (lane == 0) wsum[wid] = v;
  __syncthreads();
  if (threadIdx.x == 0) bsum[blockIdx.x] = wsum[0]+wsum[1]+wsum[2]+wsum[3];
}

__global__ __launch_bounds__(256) void k_scan_mid(const unsigned* __restrict__ bsum,
                                                  unsigned* __restrict__ boff)
{
  const int t = threadIdx.x;
  const unsigned v = (t < NB) ? bsum[t] : 0u;
  unsigned inc = v;
  const int lane = t & 63, wid = t >> 6;
  #pragma unroll
  for (int o = 1; o < 64; o <<= 1) {
    const unsigned u = __shfl_up(inc, o, 64);
    if (lane >= o) inc += u;
  }
  __shared__ unsigned wsum[4], woff[4];
  if (lane == 63) wsum[wid] = inc;
  __syncthreads();
  if (t == 0) { unsigned run = 0; for (int i=0;i<4;++i){ woff[i]=run; run+=wsum[i]; } }
  __syncthreads();
  if (t < NB) boff[t] = woff[wid] + inc - v;
}

__global__ __launch_bounds__(256) void k_scan_exp(const unsigned* __restrict__ counts,
    const unsigned* __restrict__ boff,
    unsigned* __restrict__ rowptr, unsigned* __restrict__ fill)
{
  const int idx = blockIdx.x*256 + threadIdx.x;
  const unsigned v = (idx < NN) ? counts[idx] : 0u;
  unsigned inc = v;
  const int lane = threadIdx.x & 63, wid = threadIdx.x >> 6;
  #pragma unroll
  for (int o = 1; o < 64; o <<= 1) {
    const unsigned u = __shfl_up(inc, o, 64);
    if (lane >= o) inc += u;
  }
  __shared__ unsigned wsum[4], woff[4];
  if (lane == 63) wsum[wid] = inc;
  __syncthreads();
  if (threadIdx.x == 0) { unsigned run = 0; for (int i=0;i<4;++i){ woff[i]=run; run+=wsum[i]; } }
  __syncthreads();
  const unsigned exc = boff[blockIdx.x] + woff[wid] + inc - v;
  if (idx < NN) { rowptr[idx] = exc; fill[idx] = exc; }
  if (idx == 0) rowptr[NN] = ET;
}

__global__ __launch_bounds__(256) void k_scatter(const int* __restrict__ ei,
    unsigned* __restrict__ fill, unsigned* __restrict__ srcs)
{
  const int e = blockIdx.x*256 + threadIdx.x;
  if (e >= ET) return;
  int s, d;
  if (e < NE) { s = ei[e]; d = ei[NE + e]; } else { s = e - NE; d = s; }
  const unsigned pos = atomicAdd(&fill[d], 1u);
  srcs[pos] = (unsigned)s;
}

// ---------------- Layer-1 aggregate + bias/ELU + Layer-2 linear + alpha2 ----------------
// Round-9: TWO waves per node (halves the serial per-wave edge chain).
// Block = 256 thd = 4 waves = 2 nodes; 25000 blocks (50000 = exact).
// Each wave stages+gathers half the node's edges; partials combined in LDS.
__global__ __launch_bounds__(256) void k_agg1(
    const unsigned* __restrict__ rowptr, const unsigned* __restrict__ srcs,
    const unsigned* __restrict__ h1b, const float* __restrict__ as1,
    const float* __restrict__ ad1, const float* __restrict__ b1,
    const float* __restrict__ W2, const float* __restrict__ a_src2,
    const float* __restrict__ a_dst2,
    float* __restrict__ g, float* __restrict__ as2v, float* __restrict__ ad2v)
{
  __shared__ unsigned sh_src[4][64];
  __shared__ float    sh_w[4][64][4];
  __shared__ float    sh_acc[2][128];   // per-node partial acc from half-1 wave
  __shared__ float    sh_sw[2][4];      // per-node partial weight sums from half-1
  const int lane = threadIdx.x & 63;
  const int wv   = threadIdx.x >> 6;    // 0..3
  const int slot = wv >> 1;             // node slot in block: 0..1
  const int half = wv & 1;              // 0 or 1
  const int n = blockIdx.x*2 + slot;
  const unsigned nbeg = rowptr[n], nend = rowptr[n+1];
  const unsigned mid = nbeg + ((nend - nbeg) >> 1);
  const unsigned beg = half ? mid : nbeg;
  const unsigned end = half ? nend : mid;
  const float4 ad = *(const float4*)&ad1[(size_t)n*4];
  const int h = lane >> 4;

  float acc0 = 0.f, acc1 = 0.f;
  float sw0 = 0.f, sw1 = 0.f, sw2 = 0.f, sw3 = 0.f;

  for (unsigned base = beg; base < end; base += 64) {
    const unsigned i = base + (unsigned)lane;
    if (i < end) {
      const unsigned s = srcs[i];
      const float4 as = *(const float4*)&as1[(size_t)s*4];
      const float w0 = __expf(lrelu(as.x + ad.x));
      const float w1 = __expf(lrelu(as.y + ad.y));
      const float w2 = __expf(lrelu(as.z + ad.z));
      const float w3 = __expf(lrelu(as.w + ad.w));
      sw0 += w0; sw1 += w1; sw2 += w2; sw3 += w3;
      sh_src[wv][lane] = s;
      *(float4*)&sh_w[wv][lane][0] = make_float4(w0,w1,w2,w3);
    }
    __builtin_amdgcn_wave_barrier();

    const int cnt = (int)((end - base < 64u) ? (end - base) : 64u);
    int j = 0;
    for (; j + 7 < cnt; j += 8) {
      unsigned off[8]; float wvv[8]; unsigned uv[8];
      #pragma unroll
      for (int q=0;q<8;++q) {
        off[q] = (sh_src[wv][j+q] << 6) | (unsigned)lane;
        wvv[q] = sh_w[wv][j+q][h];
      }
      #pragma unroll
      for (int q=0;q<8;++q) uv[q] = h1b[off[q]];
      #pragma unroll
      for (int q=0;q<8;++q) {
        acc0 += wvv[q]*bf_lo(uv[q]);
        acc1 += wvv[q]*bf_hi(uv[q]);
      }
    }
    for (; j < cnt; ++j) {
      const unsigned off = (sh_src[wv][j] << 6) | (unsigned)lane;
      const float w0 = sh_w[wv][j][h];
      const unsigned u = h1b[off];
      acc0 += w0*bf_lo(u); acc1 += w0*bf_hi(u);
    }
    __builtin_amdgcn_wave_barrier();
  }

  // per-wave reduce of weight sums
  #pragma unroll
  for (int o = 1; o < 64; o <<= 1) {
    sw0 += __shfl_xor(sw0, o); sw1 += __shfl_xor(sw1, o);
    sw2 += __shfl_xor(sw2, o); sw3 += __shfl_xor(sw3, o);
  }

  // half-1 publishes partials; half-0 combines and runs epilogue
  if (half) {
    sh_acc[slot][lane*2]     = acc0;
    sh_acc[slot][lane*2 + 1] = acc1;
    if (lane == 0) {
      sh_sw[slot][0] = sw0; sh_sw[slot][1] = sw1;
      sh_sw[slot][2] = sw2; sh_sw[slot][3] = sw3;
    }
  }
  __syncthreads();
  if (half) return;

  acc0 += sh_acc[slot][lane*2];
  acc1 += sh_acc[slot][lane*2 + 1];
  sw0 += sh_sw[slot][0]; sw1 += sh_sw[slot][1];
  sw2 += sh_sw[slot][2]; sw3 += sh_sw[slot][3];

  const float swh = (h==0)?sw0:(h==1)?sw1:(h==2)?sw2:sw3;
  const float inv = 1.0f / swh;

  const int c0 = lane*2;
  const float2 bb = *(const float2*)&b1[c0];
  const float e0 = eluf(acc0*inv + bb.x);
  const float e1 = eluf(acc1*inv + bb.y);

  const float4 wa0 = *(const float4*)&W2[(size_t)c0*8];
  const float4 wa1 = *(const float4*)&W2[(size_t)c0*8 + 4];
  const float4 wb0 = *(const float4*)&W2[(size_t)(c0+1)*8];
  const float4 wb1 = *(const float4*)&W2[(size_t)(c0+1)*8 + 4];
  float p0 = e0*wa0.x + e1*wb0.x;
  float p1 = e0*wa0.y + e1*wb0.y;
  float p2 = e0*wa0.z + e1*wb0.z;
  float p3 = e0*wa0.w + e1*wb0.w;
  float p4 = e0*wa1.x + e1*wb1.x;
  float p5 = e0*wa1.y + e1*wb1.y;
  float p6 = e0*wa1.z + e1*wb1.z;
  float p7 = e0*wa1.w + e1*wb1.w;
  #pragma unroll
  for (int o = 1; o < 64; o <<= 1) {
    p0 += __shfl_xor(p0, o); p1 += __shfl_xor(p1, o);
    p2 += __shfl_xor(p2, o); p3 += __shfl_xor(p3, o);
    p4 += __shfl_xor(p4, o); p5 += __shfl_xor(p5, o);
    p6 += __shfl_xor(p6, o); p7 += __shfl_xor(p7, o);
  }
  if (lane == 0) {
    *(float4*)&g[(size_t)n*8]     = make_float4(p0,p1,p2,p3);
    *(float4*)&g[(size_t)n*8 + 4] = make_float4(p4,p5,p6,p7);
    const float s2 = p0*a_src2[0]+p1*a_src2[1]+p2*a_src2[2]+p3*a_src2[3]
                   + p4*a_src2[4]+p5*a_src2[5]+p6*a_src2[6]+p7*a_src2[7];
    const float d2 = p0*a_dst2[0]+p1*a_dst2[1]+p2*a_dst2[2]+p3*a_dst2[3]
                   + p4*a_dst2[4]+p5*a_dst2[5]+p6*a_dst2[6]+p7*a_dst2[7];
    as2v[n] = s2; ad2v[n] = d2;
  }
}

// ---------------- Layer-2 aggregate -> output ----------------
__global__ __launch_bounds__(256) void k_agg2(
    const unsigned* __restrict__ rowptr, const unsigned* __restrict__ srcs,
    const float* __restrict__ g, const float* __restrict__ as2v,
    const float* __restrict__ ad2v, const float* __restrict__ b2,
    float* __restrict__ out)
{
  const int lane = threadIdx.x & 63;
  const int n = blockIdx.x*4 + (threadIdx.x >> 6);
  if (n >= NN) return;
  const unsigned beg = rowptr[n], end = rowptr[n+1];
  const float adv = ad2v[n];

  float a0=0.f,a1=0.f,a2=0.f,a3=0.f,a4=0.f,a5=0.f,a6=0.f,a7=0.f,sw=0.f;
  for (unsigned i = beg + lane; i < end; i += 64) {
    const unsigned s = srcs[i];
    const float w = __expf(lrelu(as2v[s] + adv));
    sw += w;
    const float4 ga = *(const float4*)&g[(size_t)s*8];
    const float4 gb = *(const float4*)&g[(size_t)s*8 + 4];
    a0 += w*ga.x; a1 += w*ga.y; a2 += w*ga.z; a3 += w*ga.w;
    a4 += w*gb.x; a5 += w*gb.y; a6 += w*gb.z; a7 += w*gb.w;
  }
  #pragma unroll
  for (int o = 1; o < 64; o <<= 1) {
    sw += __shfl_xor(sw, o);
    a0 += __shfl_xor(a0, o); a1 += __shfl_xor(a1, o);
    a2 += __shfl_xor(a2, o); a3 += __shfl_xor(a3, o);
    a4 += __shfl_xor(a4, o); a5 += __shfl_xor(a5, o);
    a6 += __shfl_xor(a6, o); a7 += __shfl_xor(a7, o);
  }
  if (lane == 0) {
    const float inv = 1.0f / sw;
    *(float4*)&out[(size_t)n*8] =
        make_float4(a0*inv + b2[0], a1*inv + b2[1], a2*inv + b2[2], a3*inv + b2[3]);
    *(float4*)&out[(size_t)n*8 + 4] =
        make_float4(a4*inv + b2[4], a5*inv + b2[5], a6*inv + b2[6], a7*inv + b2[7]);
  }
}

// ---------------- launch ----------------
extern "C" void kernel_launch(void* const* d_in, const int* in_sizes, int n_in,
                              void* d_out, int out_size, void* d_ws, size_t ws_size,
                              hipStream_t stream) {
  const float* x      = (const float*)d_in[0];
  const int*   ei     = (const int*)d_in[1];
  const float* W1     = (const float*)d_in[2];
  const float* a_src1 = (const float*)d_in[3];
  const float* a_dst1 = (const float*)d_in[4];
  const float* b1     = (const float*)d_in[5];
  const float* W2     = (const float*)d_in[6];
  const float* a_src2 = (const float*)d_in[7];
  const float* a_dst2 = (const float*)d_in[8];
  const float* b2     = (const float*)d_in[9];
  float* out = (float*)d_out;

  char* ws = (char*)d_ws;
  unsigned* h1b    = (unsigned*)(ws + 0);                 // 12,800,000 B used
  float*    as1    = (float*)(ws + 25600000);             //    800,000
  float*    ad1    = (float*)(ws + 26400000);             //    800,000
  float*    g      = (float*)(ws + 27200000);             //  1,600,000
  float*    as2v   = (float*)(ws + 28800000);             //    200,000
  float*    ad2v   = (float*)(ws + 29000000);             //    200,000
  unsigned* counts = (unsigned*)(ws + 29200000);          //    200,000
  unsigned* rowptr = (unsigned*)(ws + 29400000);          //    200,016
  unsigned* fill   = (unsigned*)(ws + 29600016);          //    200,000
  unsigned* srcs   = (unsigned*)(ws + 29800016);          //  3,400,000
  unsigned* bsum   = (unsigned*)(ws + 33200016);          //        784
  unsigned* boff   = (unsigned*)(ws + 33201600);          //        784

  hipMemsetAsync(counts, 0, NN*sizeof(unsigned), stream);

  k_gemm<<<(NN + 63)/64, 256, 0, stream>>>(x, W1, a_src1, a_dst1, h1b, as1, ad1);
  k_hist<<<(ET + 255)/256, 256, 0, stream>>>(ei, counts);
  k_scan_part<<<NB, 256, 0, stream>>>(counts, bsum);
  k_scan_mid<<<1, 256, 0, stream>>>(bsum, boff);
  k_scan_exp<<<NB, 256, 0, stream>>>(counts, boff, rowptr, fill);
  k_scatter<<<(ET + 255)/256, 256, 0, stream>>>(ei, fill, srcs);
  k_agg1<<<NN/2, 256, 0, stream>>>(rowptr, srcs, h1b, as1, ad1, b1,
                                   W2, a_src2, a_dst2, g, as2v, ad2v);
  k_agg2<<<(NN + 3)/4, 256, 0, stream>>>(rowptr, srcs, g, as2v, ad2v, b2, out);
}

// Round 11
// 272.084 us; speedup vs baseline: 1.1821x; 1.1821x over previous
//
#include <hip/hip_runtime.h>
#include <hip/hip_bf16.h>
#include <math.h>

#define NN 50000       // nodes
#define NE 800000      // raw edges
#define ET 850000      // edges incl. self-loops
#define FIN 128
#define HTOT 128       // 4 heads * 32
#define OUTC 8
#define NB ((NN + 255) / 256)   // 196 scan blocks
#define XLD 132        // padded LDS stride for x tile
#define GEMM_THREADS (782*256)  // gemm grid size in threads (for fused hist stride)

__device__ __forceinline__ float lrelu(float v){ return v > 0.f ? v : 0.2f*v; }
__device__ __forceinline__ float eluf(float v){ return v > 0.f ? v : expm1f(v); }

__device__ __forceinline__ unsigned pack_bf16(float a, float b){
  __hip_bfloat16 ha = __float2bfloat16(a);
  __hip_bfloat16 hb = __float2bfloat16(b);
  const unsigned short ua = *(const unsigned short*)&ha;
  const unsigned short ub = *(const unsigned short*)&hb;
  return ((unsigned)ub << 16) | (unsigned)ua;
}
__device__ __forceinline__ float bf_lo(unsigned u){ return __int_as_float((int)(u << 16)); }
__device__ __forceinline__ float bf_hi(unsigned u){ return __int_as_float((int)(u & 0xffff0000u)); }

// ---------------- Layer-1 GEMM (x @ W1) + alphas + FUSED edge histogram ----------------
__global__ __launch_bounds__(256) void k_gemm(
    const float* __restrict__ x, const float* __restrict__ W1,
    const float* __restrict__ a_src1, const float* __restrict__ a_dst1,
    unsigned* __restrict__ h1b, float* __restrict__ as1, float* __restrict__ ad1,
    const int* __restrict__ ei, unsigned* __restrict__ counts)
{
  __shared__ float xl[64 * XLD];
  const int t = threadIdx.x;
  const int r0 = blockIdx.x * 64;

  #pragma unroll
  for (int i = 0; i < 8; ++i) {
    const int f   = i*256 + t;
    const int row = f >> 5;
    const int c4  = f & 31;
    const int gr  = r0 + row;
    float4 v = make_float4(0.f,0.f,0.f,0.f);
    if (gr < NN) v = *(const float4*)&x[(size_t)gr*FIN + c4*4];
    *(float4*)&xl[row*XLD + c4*4] = v;
  }
  __syncthreads();

  const int tx = t & 15, ty = t >> 4;
  const int c0a = tx*4;
  const int c0b = 64 + tx*4;

  float acc[4][8];
  #pragma unroll
  for (int i=0;i<4;++i)
    #pragma unroll
    for (int j=0;j<8;++j) acc[i][j] = 0.f;

  for (int k = 0; k < 128; k += 4) {
    float4 xv[4];
    #pragma unroll
    for (int i=0;i<4;++i)
      xv[i] = *(const float4*)&xl[(ty*4+i)*XLD + k];
    #pragma unroll
    for (int kk = 0; kk < 4; ++kk) {
      const float4 wa = *(const float4*)&W1[(size_t)(k+kk)*128 + c0a];
      const float4 wb = *(const float4*)&W1[(size_t)(k+kk)*128 + c0b];
      #pragma unroll
      for (int i=0;i<4;++i) {
        const float xk = (kk==0)?xv[i].x:(kk==1)?xv[i].y:(kk==2)?xv[i].z:xv[i].w;
        acc[i][0] += xk*wa.x; acc[i][1] += xk*wa.y; acc[i][2] += xk*wa.z; acc[i][3] += xk*wa.w;
        acc[i][4] += xk*wb.x; acc[i][5] += xk*wb.y; acc[i][6] += xk*wb.z; acc[i][7] += xk*wb.w;
      }
    }
  }

  #pragma unroll
  for (int i=0;i<4;++i) {
    const int gr = r0 + ty*4 + i;
    if (gr < NN) {
      uint2 ua, ub;
      ua.x = pack_bf16(acc[i][0], acc[i][1]);
      ua.y = pack_bf16(acc[i][2], acc[i][3]);
      ub.x = pack_bf16(acc[i][4], acc[i][5]);
      ub.y = pack_bf16(acc[i][6], acc[i][7]);
      *(uint2*)&h1b[(size_t)gr*64 + tx*2]      = ua;
      *(uint2*)&h1b[(size_t)gr*64 + 32 + tx*2] = ub;
    }
  }

  float sa[4], sb[4], da[4], db[4];
  {
    const float4 v0 = *(const float4*)&a_src1[c0a];
    const float4 v1 = *(const float4*)&a_src1[c0b];
    const float4 v2 = *(const float4*)&a_dst1[c0a];
    const float4 v3 = *(const float4*)&a_dst1[c0b];
    sa[0]=v0.x; sa[1]=v0.y; sa[2]=v0.z; sa[3]=v0.w;
    sb[0]=v1.x; sb[1]=v1.y; sb[2]=v1.z; sb[3]=v1.w;
    da[0]=v2.x; da[1]=v2.y; da[2]=v2.z; da[3]=v2.w;
    db[0]=v3.x; db[1]=v3.y; db[2]=v3.z; db[3]=v3.w;
  }
  const int ha = tx >> 3;
  #pragma unroll
  for (int i=0;i<4;++i) {
    float psa = 0.f, pda = 0.f, psb = 0.f, pdb = 0.f;
    #pragma unroll
    for (int j=0;j<4;++j) {
      psa += acc[i][j]  *sa[j]; pda += acc[i][j]  *da[j];
      psb += acc[i][4+j]*sb[j]; pdb += acc[i][4+j]*db[j];
    }
    psa += __shfl_xor(psa,1); psa += __shfl_xor(psa,2); psa += __shfl_xor(psa,4);
    pda += __shfl_xor(pda,1); pda += __shfl_xor(pda,2); pda += __shfl_xor(pda,4);
    psb += __shfl_xor(psb,1); psb += __shfl_xor(psb,2); psb += __shfl_xor(psb,4);
    pdb += __shfl_xor(pdb,1); pdb += __shfl_xor(pdb,2); pdb += __shfl_xor(pdb,4);
    const int gr = r0 + ty*4 + i;
    if ((tx & 7) == 0 && gr < NN) {
      as1[(size_t)gr*4 + ha]     = psa;
      ad1[(size_t)gr*4 + ha]     = pda;
      as1[(size_t)gr*4 + ha + 2] = psb;
      ad1[(size_t)gr*4 + ha + 2] = pdb;
    }
  }

  // fused edge histogram (grid-stride over edges; ~4-5 atomics/thread)
  const int tid = blockIdx.x*256 + t;
  for (int e = tid; e < ET; e += GEMM_THREADS) {
    const int d = (e < NE) ? ei[NE + e] : (e - NE);
    atomicAdd(&counts[d], 1u);
  }
}

// ---------------- CSR scan + scatter ----------------
__global__ __launch_bounds__(256) void k_scan_part(const unsigned* __restrict__ counts,
                                                   unsigned* __restrict__ bsum)
{
  const int idx = blockIdx.x*256 + threadIdx.x;
  unsigned v = (idx < NN) ? counts[idx] : 0u;
  #pragma unroll
  for (int o = 1; o < 64; o <<= 1) v += __shfl_xor(v, o);
  __shared__ unsigned wsum[4];
  const int lane = threadIdx.x & 63, wid = threadIdx.x >> 6;
  if (lane == 0) wsum[wid] = v;
  __syncthreads();
  if (threadIdx.x == 0) bsum[blockIdx.x] = wsum[0]+wsum[1]+wsum[2]+wsum[3];
}

__global__ __launch_bounds__(256) void k_scan_mid(const unsigned* __restrict__ bsum,
                                                  unsigned* __restrict__ boff)
{
  const int t = threadIdx.x;
  const unsigned v = (t < NB) ? bsum[t] : 0u;
  unsigned inc = v;
  const int lane = t & 63, wid = t >> 6;
  #pragma unroll
  for (int o = 1; o < 64; o <<= 1) {
    const unsigned u = __shfl_up(inc, o, 64);
    if (lane >= o) inc += u;
  }
  __shared__ unsigned wsum[4], woff[4];
  if (lane == 63) wsum[wid] = inc;
  __syncthreads();
  if (t == 0) { unsigned run = 0; for (int i=0;i<4;++i){ woff[i]=run; run+=wsum[i]; } }
  __syncthreads();
  if (t < NB) boff[t] = woff[wid] + inc - v;
}

__global__ __launch_bounds__(256) void k_scan_exp(const unsigned* __restrict__ counts,
    const unsigned* __restrict__ boff,
    unsigned* __restrict__ rowptr, unsigned* __restrict__ fill)
{
  const int idx = blockIdx.x*256 + threadIdx.x;
  const unsigned v = (idx < NN) ? counts[idx] : 0u;
  unsigned inc = v;
  const int lane = threadIdx.x & 63, wid = threadIdx.x >> 6;
  #pragma unroll
  for (int o = 1; o < 64; o <<= 1) {
    const unsigned u = __shfl_up(inc, o, 64);
    if (lane >= o) inc += u;
  }
  __shared__ unsigned wsum[4], woff[4];
  if (lane == 63) wsum[wid] = inc;
  __syncthreads();
  if (threadIdx.x == 0) { unsigned run = 0; for (int i=0;i<4;++i){ woff[i]=run; run+=wsum[i]; } }
  __syncthreads();
  const unsigned exc = boff[blockIdx.x] + woff[wid] + inc - v;
  if (idx < NN) { rowptr[idx] = exc; fill[idx] = exc; }
  if (idx == 0) rowptr[NN] = ET;
}

__global__ __launch_bounds__(256) void k_scatter(const int* __restrict__ ei,
    unsigned* __restrict__ fill, unsigned* __restrict__ srcs)
{
  const int e = blockIdx.x*256 + threadIdx.x;
  if (e >= ET) return;
  int s, d;
  if (e < NE) { s = ei[e]; d = ei[NE + e]; } else { s = e - NE; d = s; }
  const unsigned pos = atomicAdd(&fill[d], 1u);
  srcs[pos] = (unsigned)s;
}

// ---------------- Layer-1 aggregate + bias/ELU + Layer-2 linear + alpha2 ----------------
// round-8 proven version: ONE wave per node, LDS stage-then-gather, x8 unroll.
__global__ __launch_bounds__(256) void k_agg1(
    const unsigned* __restrict__ rowptr, const unsigned* __restrict__ srcs,
    const unsigned* __restrict__ h1b, const float* __restrict__ as1,
    const float* __restrict__ ad1, const float* __restrict__ b1,
    const float* __restrict__ W2, const float* __restrict__ a_src2,
    const float* __restrict__ a_dst2,
    float* __restrict__ g, float* __restrict__ as2v, float* __restrict__ ad2v)
{
  __shared__ unsigned sh_src[4][64];
  __shared__ float    sh_w[4][64][4];
  const int lane = threadIdx.x & 63;
  const int wv   = threadIdx.x >> 6;
  const int n = blockIdx.x*4 + wv;
  if (n >= NN) return;
  const unsigned beg = rowptr[n], end = rowptr[n+1];
  const float4 ad = *(const float4*)&ad1[(size_t)n*4];
  const int h = lane >> 4;

  float acc0 = 0.f, acc1 = 0.f;
  float sw0 = 0.f, sw1 = 0.f, sw2 = 0.f, sw3 = 0.f;

  for (unsigned base = beg; base < end; base += 64) {
    const unsigned i = base + (unsigned)lane;
    if (i < end) {
      const unsigned s = srcs[i];
      const float4 as = *(const float4*)&as1[(size_t)s*4];
      const float w0 = __expf(lrelu(as.x + ad.x));
      const float w1 = __expf(lrelu(as.y + ad.y));
      const float w2 = __expf(lrelu(as.z + ad.z));
      const float w3 = __expf(lrelu(as.w + ad.w));
      sw0 += w0; sw1 += w1; sw2 += w2; sw3 += w3;
      sh_src[wv][lane] = s;
      *(float4*)&sh_w[wv][lane][0] = make_float4(w0,w1,w2,w3);
    }
    __builtin_amdgcn_wave_barrier();

    const int cnt = (int)((end - base < 64u) ? (end - base) : 64u);
    int j = 0;
    for (; j + 7 < cnt; j += 8) {
      unsigned sv[8]; float wvv[8]; unsigned uv[8];
      #pragma unroll
      for (int q=0;q<8;++q) { sv[q] = sh_src[wv][j+q]; wvv[q] = sh_w[wv][j+q][h]; }
      #pragma unroll
      for (int q=0;q<8;++q) uv[q] = h1b[(size_t)sv[q]*64 + lane];
      #pragma unroll
      for (int q=0;q<8;++q) {
        acc0 += wvv[q]*bf_lo(uv[q]);
        acc1 += wvv[q]*bf_hi(uv[q]);
      }
    }
    for (; j < cnt; ++j) {
      const unsigned s0 = sh_src[wv][j];
      const float w0 = sh_w[wv][j][h];
      const unsigned u = h1b[(size_t)s0*64 + lane];
      acc0 += w0*bf_lo(u); acc1 += w0*bf_hi(u);
    }
    __builtin_amdgcn_wave_barrier();
  }

  #pragma unroll
  for (int o = 1; o < 64; o <<= 1) {
    sw0 += __shfl_xor(sw0, o); sw1 += __shfl_xor(sw1, o);
    sw2 += __shfl_xor(sw2, o); sw3 += __shfl_xor(sw3, o);
  }
  const float swh = (h==0)?sw0:(h==1)?sw1:(h==2)?sw2:sw3;
  const float inv = 1.0f / swh;

  const int c0 = lane*2;
  const float2 bb = *(const float2*)&b1[c0];
  const float e0 = eluf(acc0*inv + bb.x);
  const float e1 = eluf(acc1*inv + bb.y);

  const float4 wa0 = *(const float4*)&W2[(size_t)c0*8];
  const float4 wa1 = *(const float4*)&W2[(size_t)c0*8 + 4];
  const float4 wb0 = *(const float4*)&W2[(size_t)(c0+1)*8];
  const float4 wb1 = *(const float4*)&W2[(size_t)(c0+1)*8 + 4];
  float p0 = e0*wa0.x + e1*wb0.x;
  float p1 = e0*wa0.y + e1*wb0.y;
  float p2 = e0*wa0.z + e1*wb0.z;
  float p3 = e0*wa0.w + e1*wb0.w;
  float p4 = e0*wa1.x + e1*wb1.x;
  float p5 = e0*wa1.y + e1*wb1.y;
  float p6 = e0*wa1.z + e1*wb1.z;
  float p7 = e0*wa1.w + e1*wb1.w;
  #pragma unroll
  for (int o = 1; o < 64; o <<= 1) {
    p0 += __shfl_xor(p0, o); p1 += __shfl_xor(p1, o);
    p2 += __shfl_xor(p2, o); p3 += __shfl_xor(p3, o);
    p4 += __shfl_xor(p4, o); p5 += __shfl_xor(p5, o);
    p6 += __shfl_xor(p6, o); p7 += __shfl_xor(p7, o);
  }
  if (lane == 0) {
    *(float4*)&g[(size_t)n*8]     = make_float4(p0,p1,p2,p3);
    *(float4*)&g[(size_t)n*8 + 4] = make_float4(p4,p5,p6,p7);
    const float s2 = p0*a_src2[0]+p1*a_src2[1]+p2*a_src2[2]+p3*a_src2[3]
                   + p4*a_src2[4]+p5*a_src2[5]+p6*a_src2[6]+p7*a_src2[7];
    const float d2 = p0*a_dst2[0]+p1*a_dst2[1]+p2*a_dst2[2]+p3*a_dst2[3]
                   + p4*a_dst2[4]+p5*a_dst2[5]+p6*a_dst2[6]+p7*a_dst2[7];
    as2v[n] = s2; ad2v[n] = d2;
  }
}

// ---------------- Layer-2 aggregate -> output ----------------
// 16-lane group per node (4 nodes/wave, 16/block; grid 3125 exact).
__global__ __launch_bounds__(256) void k_agg2(
    const unsigned* __restrict__ rowptr, const unsigned* __restrict__ srcs,
    const float* __restrict__ g, const float* __restrict__ as2v,
    const float* __restrict__ ad2v, const float* __restrict__ b2,
    float* __restrict__ out)
{
  const int lane = threadIdx.x & 63;
  const int gl   = lane & 15;           // lane within 16-group
  const int n = blockIdx.x*16 + (threadIdx.x >> 6)*4 + (lane >> 4);
  const unsigned beg = rowptr[n], end = rowptr[n+1];
  const float adv = ad2v[n];

  float a0=0.f,a1=0.f,a2=0.f,a3=0.f,a4=0.f,a5=0.f,a6=0.f,a7=0.f,sw=0.f;
  for (unsigned i = beg + gl; i < end; i += 16) {
    const unsigned s = srcs[i];
    const float w = __expf(lrelu(as2v[s] + adv));
    sw += w;
    const float4 ga = *(const float4*)&g[(size_t)s*8];
    const float4 gb = *(const float4*)&g[(size_t)s*8 + 4];
    a0 += w*ga.x; a1 += w*ga.y; a2 += w*ga.z; a3 += w*ga.w;
    a4 += w*gb.x; a5 += w*gb.y; a6 += w*gb.z; a7 += w*gb.w;
  }
  #pragma unroll
  for (int o = 1; o < 16; o <<= 1) {
    sw += __shfl_xor(sw, o);
    a0 += __shfl_xor(a0, o); a1 += __shfl_xor(a1, o);
    a2 += __shfl_xor(a2, o); a3 += __shfl_xor(a3, o);
    a4 += __shfl_xor(a4, o); a5 += __shfl_xor(a5, o);
    a6 += __shfl_xor(a6, o); a7 += __shfl_xor(a7, o);
  }
  if (gl == 0) {
    const float inv = 1.0f / sw;
    *(float4*)&out[(size_t)n*8] =
        make_float4(a0*inv + b2[0], a1*inv + b2[1], a2*inv + b2[2], a3*inv + b2[3]);
    *(float4*)&out[(size_t)n*8 + 4] =
        make_float4(a4*inv + b2[4], a5*inv + b2[5], a6*inv + b2[6], a7*inv + b2[7]);
  }
}

// ---------------- launch ----------------
extern "C" void kernel_launch(void* const* d_in, const int* in_sizes, int n_in,
                              void* d_out, int out_size, void* d_ws, size_t ws_size,
                              hipStream_t stream) {
  const float* x      = (const float*)d_in[0];
  const int*   ei     = (const int*)d_in[1];
  const float* W1     = (const float*)d_in[2];
  const float* a_src1 = (const float*)d_in[3];
  const float* a_dst1 = (const float*)d_in[4];
  const float* b1     = (const float*)d_in[5];
  const float* W2     = (const float*)d_in[6];
  const float* a_src2 = (const float*)d_in[7];
  const float* a_dst2 = (const float*)d_in[8];
  const float* b2     = (const float*)d_in[9];
  float* out = (float*)d_out;

  char* ws = (char*)d_ws;
  unsigned* h1b    = (unsigned*)(ws + 0);                 // 12,800,000 B used
  float*    as1    = (float*)(ws + 25600000);             //    800,000
  float*    ad1    = (float*)(ws + 26400000);             //    800,000
  float*    g      = (float*)(ws + 27200000);             //  1,600,000
  float*    as2v   = (float*)(ws + 28800000);             //    200,000
  float*    ad2v   = (float*)(ws + 29000000);             //    200,000
  unsigned* counts = (unsigned*)(ws + 29200000);          //    200,000
  unsigned* rowptr = (unsigned*)(ws + 29400000);          //    200,016
  unsigned* fill   = (unsigned*)(ws + 29600016);          //    200,000
  unsigned* srcs   = (unsigned*)(ws + 29800016);          //  3,400,000
  unsigned* bsum   = (unsigned*)(ws + 33200016);          //        784
  unsigned* boff   = (unsigned*)(ws + 33201600);          //        784

  hipMemsetAsync(counts, 0, NN*sizeof(unsigned), stream);

  k_gemm<<<(NN + 63)/64, 256, 0, stream>>>(x, W1, a_src1, a_dst1, h1b, as1, ad1,
                                           ei, counts);
  k_scan_part<<<NB, 256, 0, stream>>>(counts, bsum);
  k_scan_mid<<<1, 256, 0, stream>>>(bsum, boff);
  k_scan_exp<<<NB, 256, 0, stream>>>(counts, boff, rowptr, fill);
  k_scatter<<<(ET + 255)/256, 256, 0, stream>>>(ei, fill, srcs);
  k_agg1<<<(NN + 3)/4, 256, 0, stream>>>(rowptr, srcs, h1b, as1, ad1, b1,
                                         W2, a_src2, a_dst2, g, as2v, ad2v);
  k_agg2<<<NN/16, 256, 0, stream>>>(rowptr, srcs, g, as2v, ad2v, b2, out);
}